// Round 5
// baseline (204.708 us; speedup 1.0000x reference)
//
#include <hip/hip_runtime.h>
#include <cmath>

// Problem constants: (N,C,H,W) = (16,3,512,512), fp32
#define PLANE (512*512)          // 262144
#define NPLANES 48               // N*C
#define NEL (48*PLANE)           // 12582912

struct Taps { float k[9]; };
struct CMat { float w[3][3]; };   // C-axis 9-tap blur collapsed to 3x3 matrix

// ws layout for the HW-blurred logs (TILED for k_cn_loss locality):
//   index(p, h, w) = ((h*8 + (w>>6))*96 + p)*64 + (w&63)
//   p in [0,48) = image E planes, [48,96) = image G planes.

// ---------------------------------------------------------------------------
// Kernel 1: fused log + W-blur + H-blur. One WAVE per 8-row strip of one
// plane, full 512-col width. No LDS: W-halo via shuffles, H-blur via a 9-row
// register ring (slot = j mod 9, compile-time via full unroll).
// grid (64 rowgroups, 96 planes), block 64. 6144 waves (R4 had 1536 -> 13%
// occupancy, latency-bound at 32% VALU / 32% HBM).
// ---------------------------------------------------------------------------
__global__ __launch_bounds__(64, 4)
void k_blur_hw(const float* __restrict__ inE, const float* __restrict__ inG,
               float* __restrict__ ws, Taps tp)
{
    const int l  = threadIdx.x;          // lane 0..63, owns cols 8l..8l+7
    const int r0 = blockIdx.x * 8;       // first output row of this strip
    const int z  = blockIdx.y;           // plane 0..95

    const float* src = (z < NPLANES) ? (inE + z * PLANE)
                                     : (inG + (z - NPLANES) * PLANE);

    const bool is0  = (l == 0);
    const bool is63 = (l == 63);
    const int  vout = (l >> 3) * 6144 + (l & 7) * 8;  // lane offset in tiled ws

    float ring[9][8];                    // W-blurred rows j-8..j, slot = j % 9

    // prefetch input row j=0 (plane row r0-4, folded at the top edge)
    int rp0 = r0 - 4;
    rp0 = (rp0 < 0) ? (-1 - rp0) : rp0;
    float4 a = *(const float4*)(src + rp0 * 512 + l * 8);
    float4 b = *(const float4*)(src + rp0 * 512 + l * 8 + 4);

#pragma unroll
    for (int j = 0; j < 16; ++j) {       // input rows r0-4 .. r0+11
        // prefetch row j+1 (folded; r0-4+16 <= 516 -> folds to 507)
        int rn = r0 - 4 + j + 1;
        rn = (rn < 0) ? (-1 - rn) : ((rn > 511) ? (1023 - rn) : rn);
        const float* nrp = src + rn * 512 + l * 8;
        float4 na = *(const float4*)nrp;
        float4 nb = *(const float4*)(nrp + 4);

        // log of own 8 cols
        float win[16];
        win[4]  = __logf(a.x + 1e-6f);
        win[5]  = __logf(a.y + 1e-6f);
        win[6]  = __logf(a.z + 1e-6f);
        win[7]  = __logf(a.w + 1e-6f);
        win[8]  = __logf(b.x + 1e-6f);
        win[9]  = __logf(b.y + 1e-6f);
        win[10] = __logf(b.z + 1e-6f);
        win[11] = __logf(b.w + 1e-6f);

        // halo via shuffles; image-edge mirror = reverse of own values
        float s;
        s = __shfl_up(win[8], 1);   win[0]  = is0  ? win[7]  : s;
        s = __shfl_up(win[9], 1);   win[1]  = is0  ? win[6]  : s;
        s = __shfl_up(win[10], 1);  win[2]  = is0  ? win[5]  : s;
        s = __shfl_up(win[11], 1);  win[3]  = is0  ? win[4]  : s;
        s = __shfl_down(win[4], 1); win[12] = is63 ? win[11] : s;
        s = __shfl_down(win[5], 1); win[13] = is63 ? win[10] : s;
        s = __shfl_down(win[6], 1); win[14] = is63 ? win[9]  : s;
        s = __shfl_down(win[7], 1); win[15] = is63 ? win[8]  : s;

        // W-blur -> ring slot j%9 (compile-time)
#pragma unroll
        for (int i = 0; i < 8; ++i) {
            float o = 0.f;
#pragma unroll
            for (int t = 0; t < 9; ++t) o += tp.k[t] * win[i + t];
            ring[j % 9][i] = o;
        }

        // H-blur + store once 9 rows live (output plane row r0+j-8)
        if (j >= 8) {
            float acc[8];
#pragma unroll
            for (int i = 0; i < 8; ++i) {
                float o = 0.f;
#pragma unroll
                for (int t = 0; t < 9; ++t)
                    o += tp.k[t] * ring[(j - 8 + t) % 9][i];
                acc[i] = o;
            }
            const int ro = r0 + j - 8;
            float* dp = ws + (ro * 768 + z) * 64 + vout;
            *(float4*)dp       = make_float4(acc[0], acc[1], acc[2], acc[3]);
            *(float4*)(dp + 4) = make_float4(acc[4], acc[5], acc[6], acc[7]);
        }
        a = na; b = nb;
    }
}

// ---------------------------------------------------------------------------
// Kernel 2: C-blur + N-blur + loss, register-light (9-slot ring, 3x3 C-matrix),
// with software-pipelined loads: raw ws values prefetched one ring-step ahead,
// Ie/Ig one n-iteration ahead.
// grid (1024), block (256); one thread per (h,w).
// ---------------------------------------------------------------------------
__global__ __launch_bounds__(256)
void k_cn_loss(const float* __restrict__ ws, const float* __restrict__ Ie,
               const float* __restrict__ Ig, float* __restrict__ part,
               Taps tp, CMat cm)
{
    const int tid = threadIdx.x;
    const int hw  = blockIdx.x * 256 + tid;
    const float* wbase = ws + (hw >> 6) * (96 * 64) + (hw & 63);
    // E plane q at wbase[q*64], G plane q at wbase[(48+q)*64]

    float re[9][3];   // ring of C-blurred smoothed-log(E), slot = m % 9
    float rg[9][3];

#define LOADRAW(m, vE, vG)                                                     \
    vE[0] = wbase[((m) * 3 + 0) * 64];                                         \
    vE[1] = wbase[((m) * 3 + 1) * 64];                                         \
    vE[2] = wbase[((m) * 3 + 2) * 64];                                         \
    vG[0] = wbase[(48 + (m) * 3 + 0) * 64];                                    \
    vG[1] = wbase[(48 + (m) * 3 + 1) * 64];                                    \
    vG[2] = wbase[(48 + (m) * 3 + 2) * 64];

#define CBLUR(v, dst)                                                          \
    dst[0] = cm.w[0][0] * v[0] + cm.w[0][1] * v[1] + cm.w[0][2] * v[2];        \
    dst[1] = cm.w[1][0] * v[0] + cm.w[1][1] * v[1] + cm.w[1][2] * v[2];        \
    dst[2] = cm.w[2][0] * v[0] + cm.w[2][1] * v[1] + cm.w[2][2] * v[2];

    // warmup: ring slots m=0..3
#pragma unroll
    for (int m = 0; m < 4; ++m) {
        float vE[3], vG[3];
        LOADRAW(m, vE, vG);
        CBLUR(vE, re[m]); CBLUR(vG, rg[m]);
    }
    // prefetch raw m=4 and I values for n=0
    float nvE[3], nvG[3];
    LOADRAW(4, nvE, nvG);
    float ieq[3], igq[3];
#pragma unroll
    for (int c = 0; c < 3; ++c) {
        ieq[c] = Ie[c * PLANE + hw] + 1e-6f;
        igq[c] = Ig[c * PLANE + hw] + 1e-6f;
    }

    float acc = 0.f;
#pragma unroll
    for (int n = 0; n < 16; ++n) {
        // issue next-iteration I loads first (longest latency distance)
        float nie[3], nig[3];
        if (n + 1 < 16) {
#pragma unroll
            for (int c = 0; c < 3; ++c) {
                nie[c] = Ie[((n + 1) * 3 + c) * PLANE + hw] + 1e-6f;
                nig[c] = Ig[((n + 1) * 3 + c) * PLANE + hw] + 1e-6f;
            }
        }
        // ring update from prefetched raw; prefetch next raw
        const int mnew = n + 4;
        if (mnew < 16) {
            CBLUR(nvE, re[mnew % 9]); CBLUR(nvG, rg[mnew % 9]);
            if (mnew + 1 < 16) { LOADRAW(mnew + 1, nvE, nvG); }
        }
#pragma unroll
        for (int c = 0; c < 3; ++c) {
            float se = 0.f, sg = 0.f;
#pragma unroll
            for (int t = 0; t < 9; ++t) {
                int m = n - 4 + t;
                m = (m < 0) ? (-1 - m) : ((m > 15) ? (31 - m) : m);  // compile-time
                se += tp.k[t] * re[m % 9][c];
                sg += tp.k[t] * rg[m % 9][c];
            }
            float ee = __expf(-se);                  // 1/Le
            float eg = __expf(-sg);
            float Re = ieq[c] * ee;
            float Rg = igq[c] * eg;
            float Le = __builtin_amdgcn_rcpf(ee);    // exp(se)
            float Lg = __builtin_amdgcn_rcpf(eg);
            float dr = Re - Rg;
            float dl = Le - Lg;
            acc += dr * dr + dl * dl;
        }
        if (n + 1 < 16) {
#pragma unroll
            for (int c = 0; c < 3; ++c) { ieq[c] = nie[c]; igq[c] = nig[c]; }
        }
    }
#undef LOADRAW
#undef CBLUR

    __shared__ float red[256];
    red[tid] = acc;
    __syncthreads();
#pragma unroll
    for (int s = 128; s > 0; s >>= 1) {
        if (tid < s) red[tid] += red[tid + s];
        __syncthreads();
    }
    if (tid == 0) part[blockIdx.x] = red[0];
}

// ---------------------------------------------------------------------------
// Kernel 3: reduce 1024 partials, scale by 1/NEL
// ---------------------------------------------------------------------------
__global__ __launch_bounds__(256)
void k_final(const float* __restrict__ part, float* __restrict__ out)
{
    __shared__ float red[256];
    float a = 0.f;
    for (int i = threadIdx.x; i < 1024; i += 256) a += part[i];
    red[threadIdx.x] = a;
    __syncthreads();
#pragma unroll
    for (int s = 128; s > 0; s >>= 1) {
        if (threadIdx.x < s) red[threadIdx.x] += red[threadIdx.x + s];
        __syncthreads();
    }
    if (threadIdx.x == 0) out[0] = red[0] * (1.0f / (float)NEL);
}

extern "C" void kernel_launch(void* const* d_in, const int* in_sizes, int n_in,
                              void* d_out, int out_size, void* d_ws, size_t ws_size,
                              hipStream_t stream) {
    const float* Ie = (const float*)d_in[0];
    const float* Ig = (const float*)d_in[1];

    // Gaussian taps: sigma=1, radius=int(4*1+0.5)=4, double-precision normalize
    Taps tp;
    {
        double kk[9], s = 0.0;
        for (int i = 0; i < 9; ++i) { double x = (double)(i - 4); kk[i] = exp(-0.5 * x * x); s += kk[i]; }
        for (int i = 0; i < 9; ++i) tp.k[i] = (float)(kk[i] / s);
    }

    // C-axis (size 3) 9-tap symmetric blur collapsed to a 3x3 matrix
    CMat cm;
    {
        for (int c = 0; c < 3; ++c) {
            cm.w[c][0] = cm.w[c][1] = cm.w[c][2] = 0.f;
            for (int t = 0; t < 9; ++t) {
                int m = c - 4 + t;
                int mm = ((m % 6) + 6) % 6;          // symmetric reflect, period 6
                if (mm > 2) mm = 5 - mm;
                cm.w[c][mm] += tp.k[t];
            }
        }
    }

    float* ws   = (float*)d_ws;          // tiled blurred logs, 96 MB (2*NEL floats)
    float* part = ws + 2 * (size_t)NEL;  // 1024 block partials

    dim3 g1(64, 96);
    k_blur_hw<<<g1, 64, 0, stream>>>(Ie, Ig, ws, tp);
    k_cn_loss<<<1024, 256, 0, stream>>>(ws, Ie, Ig, part, tp, cm);
    k_final<<<1, 256, 0, stream>>>(part, (float*)d_out);
}

// Round 6
// 184.087 us; speedup vs baseline: 1.1120x; 1.1120x over previous
//
#include <hip/hip_runtime.h>
#include <cmath>

// Problem constants: (N,C,H,W) = (16,3,512,512), fp32
#define PLANE (512*512)          // 262144
#define NPLANES 48               // N*C
#define NEL (48*PLANE)           // 12582912

struct Taps { float k[9]; };
struct CMat { float w[3][3]; };   // C-axis 9-tap blur collapsed to 3x3 matrix

// ws layout for the HW-blurred logs (TILED for k_cn_loss locality):
//   index(p, h, w) = ((h*8 + (w>>6))*96 + p)*64 + (w&63)
//   p in [0,48) = image E planes, [48,96) = image G planes.

// ---------------------------------------------------------------------------
// Kernel 1: fused log + W-blur + H-blur. One WAVE per 32-row strip (low halo
// amp: 40 input rows / 32 output rows = 1.25x; R5's 8-row strips had 2x and
// regressed). Latency hidden by a DEPTH-3 explicit row-load pipeline (rows
// j+1..j+3 in flight, named regs) instead of more waves. 10-row W-blur ring,
// 10-unrolled inner loop keeps all slots compile-time.
// grid (16 rowgroups, 96 planes), block 64.
// ---------------------------------------------------------------------------
__global__ __launch_bounds__(64)
void k_blur_hw(const float* __restrict__ inE, const float* __restrict__ inG,
               float* __restrict__ ws, Taps tp)
{
    const int l  = threadIdx.x;          // lane 0..63, owns cols 8l..8l+7
    const int r0 = blockIdx.x * 32;      // first output row of this strip
    const int z  = blockIdx.y;           // plane 0..95

    const float* src = (z < NPLANES) ? (inE + z * PLANE)
                                     : (inG + (z - NPLANES) * PLANE);

    const bool is0  = (l == 0);
    const bool is63 = (l == 63);
    const int  vout = (l >> 3) * 6144 + (l & 7) * 8;  // lane offset in tiled ws

    float ring[10][8];                   // W-blurred rows, slot = row_idx % 10

#define FOLD(r) ((r) < 0 ? (-1 - (r)) : ((r) > 511 ? (1023 - (r)) : (r)))

    // preload input rows 0,1,2 (plane rows r0-4 .. r0-2, folded)
    float4 a, b, c, d, e, f;
    {
        int rr;
        rr = FOLD(r0 - 4);
        a = *(const float4*)(src + rr * 512 + l * 8);
        b = *(const float4*)(src + rr * 512 + l * 8 + 4);
        rr = FOLD(r0 - 3);
        c = *(const float4*)(src + rr * 512 + l * 8);
        d = *(const float4*)(src + rr * 512 + l * 8 + 4);
        rr = FOLD(r0 - 2);
        e = *(const float4*)(src + rr * 512 + l * 8);
        f = *(const float4*)(src + rr * 512 + l * 8 + 4);
    }

    for (int jb = 0; jb < 40; jb += 10) {
#pragma unroll
        for (int u = 0; u < 10; ++u) {
            const int j = jb + u;        // input row index 0..39 (plane r0-4+j)

            // log of current row (regs a,b)
            float win[16];
            win[4]  = __logf(a.x + 1e-6f);
            win[5]  = __logf(a.y + 1e-6f);
            win[6]  = __logf(a.z + 1e-6f);
            win[7]  = __logf(a.w + 1e-6f);
            win[8]  = __logf(b.x + 1e-6f);
            win[9]  = __logf(b.y + 1e-6f);
            win[10] = __logf(b.z + 1e-6f);
            win[11] = __logf(b.w + 1e-6f);

            // rotate pipeline and issue load of row j+3 (3 loads in flight)
            a = c; b = d; c = e; d = f;
            if (j + 3 < 40) {
                int rn = FOLD(r0 - 4 + j + 3);
                const float* nrp = src + rn * 512 + l * 8;
                e = *(const float4*)nrp;
                f = *(const float4*)(nrp + 4);
            }

            // halo via shuffles; image-edge mirror = reverse of own values
            float s;
            s = __shfl_up(win[8], 1);   win[0]  = is0  ? win[7]  : s;
            s = __shfl_up(win[9], 1);   win[1]  = is0  ? win[6]  : s;
            s = __shfl_up(win[10], 1);  win[2]  = is0  ? win[5]  : s;
            s = __shfl_up(win[11], 1);  win[3]  = is0  ? win[4]  : s;
            s = __shfl_down(win[4], 1); win[12] = is63 ? win[11] : s;
            s = __shfl_down(win[5], 1); win[13] = is63 ? win[10] : s;
            s = __shfl_down(win[6], 1); win[14] = is63 ? win[9]  : s;
            s = __shfl_down(win[7], 1); win[15] = is63 ? win[8]  : s;

            // W-blur -> ring slot u (compile-time)
#pragma unroll
            for (int i = 0; i < 8; ++i) {
                float o = 0.f;
#pragma unroll
                for (int t = 0; t < 9; ++t) o += tp.k[t] * win[i + t];
                ring[u][i] = o;
            }

            // H-blur + store once 9 rows live (output plane row r0+j-8)
            if (j >= 8) {
                float acc[8];
#pragma unroll
                for (int i = 0; i < 8; ++i) {
                    float o = 0.f;
#pragma unroll
                    for (int t = 0; t < 9; ++t)
                        o += tp.k[t] * ring[(u + 2 + t) % 10][i];  // row j-8+t
                    acc[i] = o;
                }
                const int ro = r0 + j - 8;
                float* dp = ws + (ro * 768 + z) * 64 + vout;
                *(float4*)dp       = make_float4(acc[0], acc[1], acc[2], acc[3]);
                *(float4*)(dp + 4) = make_float4(acc[4], acc[5], acc[6], acc[7]);
            }
        }
    }
#undef FOLD
}

// ---------------------------------------------------------------------------
// Kernel 2: C-blur + N-blur + loss, register-light (9-slot ring, 3x3 C-matrix),
// software-pipelined loads (ws one ring-step ahead, Ie/Ig one n-iter ahead).
// grid (1024), block (256); one thread per (h,w).
// ---------------------------------------------------------------------------
__global__ __launch_bounds__(256)
void k_cn_loss(const float* __restrict__ ws, const float* __restrict__ Ie,
               const float* __restrict__ Ig, float* __restrict__ part,
               Taps tp, CMat cm)
{
    const int tid = threadIdx.x;
    const int hw  = blockIdx.x * 256 + tid;
    const float* wbase = ws + (hw >> 6) * (96 * 64) + (hw & 63);
    // E plane q at wbase[q*64], G plane q at wbase[(48+q)*64]

    float re[9][3];   // ring of C-blurred smoothed-log(E), slot = m % 9
    float rg[9][3];

#define LOADRAW(m, vE, vG)                                                     \
    vE[0] = wbase[((m) * 3 + 0) * 64];                                         \
    vE[1] = wbase[((m) * 3 + 1) * 64];                                         \
    vE[2] = wbase[((m) * 3 + 2) * 64];                                         \
    vG[0] = wbase[(48 + (m) * 3 + 0) * 64];                                    \
    vG[1] = wbase[(48 + (m) * 3 + 1) * 64];                                    \
    vG[2] = wbase[(48 + (m) * 3 + 2) * 64];

#define CBLUR(v, dst)                                                          \
    dst[0] = cm.w[0][0] * v[0] + cm.w[0][1] * v[1] + cm.w[0][2] * v[2];        \
    dst[1] = cm.w[1][0] * v[0] + cm.w[1][1] * v[1] + cm.w[1][2] * v[2];        \
    dst[2] = cm.w[2][0] * v[0] + cm.w[2][1] * v[1] + cm.w[2][2] * v[2];

#pragma unroll
    for (int m = 0; m < 4; ++m) {
        float vE[3], vG[3];
        LOADRAW(m, vE, vG);
        CBLUR(vE, re[m]); CBLUR(vG, rg[m]);
    }
    float nvE[3], nvG[3];
    LOADRAW(4, nvE, nvG);
    float ieq[3], igq[3];
#pragma unroll
    for (int c = 0; c < 3; ++c) {
        ieq[c] = Ie[c * PLANE + hw] + 1e-6f;
        igq[c] = Ig[c * PLANE + hw] + 1e-6f;
    }

    float acc = 0.f;
#pragma unroll
    for (int n = 0; n < 16; ++n) {
        float nie[3], nig[3];
        if (n + 1 < 16) {
#pragma unroll
            for (int c = 0; c < 3; ++c) {
                nie[c] = Ie[((n + 1) * 3 + c) * PLANE + hw] + 1e-6f;
                nig[c] = Ig[((n + 1) * 3 + c) * PLANE + hw] + 1e-6f;
            }
        }
        const int mnew = n + 4;
        if (mnew < 16) {
            CBLUR(nvE, re[mnew % 9]); CBLUR(nvG, rg[mnew % 9]);
            if (mnew + 1 < 16) { LOADRAW(mnew + 1, nvE, nvG); }
        }
#pragma unroll
        for (int c = 0; c < 3; ++c) {
            float se = 0.f, sg = 0.f;
#pragma unroll
            for (int t = 0; t < 9; ++t) {
                int m = n - 4 + t;
                m = (m < 0) ? (-1 - m) : ((m > 15) ? (31 - m) : m);  // compile-time
                se += tp.k[t] * re[m % 9][c];
                sg += tp.k[t] * rg[m % 9][c];
            }
            float ee = __expf(-se);                  // 1/Le
            float eg = __expf(-sg);
            float Re = ieq[c] * ee;
            float Rg = igq[c] * eg;
            float Le = __builtin_amdgcn_rcpf(ee);    // exp(se)
            float Lg = __builtin_amdgcn_rcpf(eg);
            float dr = Re - Rg;
            float dl = Le - Lg;
            acc += dr * dr + dl * dl;
        }
        if (n + 1 < 16) {
#pragma unroll
            for (int c = 0; c < 3; ++c) { ieq[c] = nie[c]; igq[c] = nig[c]; }
        }
    }
#undef LOADRAW
#undef CBLUR

    __shared__ float red[256];
    red[tid] = acc;
    __syncthreads();
#pragma unroll
    for (int s = 128; s > 0; s >>= 1) {
        if (tid < s) red[tid] += red[tid + s];
        __syncthreads();
    }
    if (tid == 0) part[blockIdx.x] = red[0];
}

// ---------------------------------------------------------------------------
// Kernel 3: reduce 1024 partials, scale by 1/NEL
// ---------------------------------------------------------------------------
__global__ __launch_bounds__(256)
void k_final(const float* __restrict__ part, float* __restrict__ out)
{
    __shared__ float red[256];
    float a = 0.f;
    for (int i = threadIdx.x; i < 1024; i += 256) a += part[i];
    red[threadIdx.x] = a;
    __syncthreads();
#pragma unroll
    for (int s = 128; s > 0; s >>= 1) {
        if (threadIdx.x < s) red[threadIdx.x] += red[threadIdx.x + s];
        __syncthreads();
    }
    if (threadIdx.x == 0) out[0] = red[0] * (1.0f / (float)NEL);
}

extern "C" void kernel_launch(void* const* d_in, const int* in_sizes, int n_in,
                              void* d_out, int out_size, void* d_ws, size_t ws_size,
                              hipStream_t stream) {
    const float* Ie = (const float*)d_in[0];
    const float* Ig = (const float*)d_in[1];

    // Gaussian taps: sigma=1, radius=int(4*1+0.5)=4, double-precision normalize
    Taps tp;
    {
        double kk[9], s = 0.0;
        for (int i = 0; i < 9; ++i) { double x = (double)(i - 4); kk[i] = exp(-0.5 * x * x); s += kk[i]; }
        for (int i = 0; i < 9; ++i) tp.k[i] = (float)(kk[i] / s);
    }

    // C-axis (size 3) 9-tap symmetric blur collapsed to a 3x3 matrix
    CMat cm;
    {
        for (int c = 0; c < 3; ++c) {
            cm.w[c][0] = cm.w[c][1] = cm.w[c][2] = 0.f;
            for (int t = 0; t < 9; ++t) {
                int m = c - 4 + t;
                int mm = ((m % 6) + 6) % 6;          // symmetric reflect, period 6
                if (mm > 2) mm = 5 - mm;
                cm.w[c][mm] += tp.k[t];
            }
        }
    }

    float* ws   = (float*)d_ws;          // tiled blurred logs, 96 MB (2*NEL floats)
    float* part = ws + 2 * (size_t)NEL;  // 1024 block partials

    dim3 g1(16, 96);
    k_blur_hw<<<g1, 64, 0, stream>>>(Ie, Ig, ws, tp);
    k_cn_loss<<<1024, 256, 0, stream>>>(ws, Ie, Ig, part, tp, cm);
    k_final<<<1, 256, 0, stream>>>(part, (float*)d_out);
}

// Round 7
// 183.184 us; speedup vs baseline: 1.1175x; 1.0049x over previous
//
#include <hip/hip_runtime.h>
#include <hip/hip_fp16.h>
#include <cmath>

// Problem constants: (N,C,H,W) = (16,3,512,512), fp32
#define PLANE (512*512)          // 262144
#define NPLANES 48               // N*C
#define NEL (48*PLANE)           // 12582912

struct Taps { float k[9]; };
struct CMat { float w[3][3]; };   // C-axis 9-tap blur collapsed to 3x3 matrix

// ws: fp16 HW-blurred logs, TILED:
//   half index(p, h, w) = ((h*8 + (w>>6))*96 + p)*64 + (w&63)
//   p in [0,48) = image E planes, [48,96) = image G planes.  48 MB total.

// ---------------------------------------------------------------------------
// Kernel 1: fused log + W-blur + H-blur. One WAVE per (32-row strip x 256-col
// half). 4 cols/lane. W-halo: lanes 1..62 via shuffle; lanes 0/63 via one
// predicated float4 load (or register mirror at the image edge). 10-row ring.
// grid (32, 96): x = (rowgroup<<1)|whalf, y = plane. 3072 waves = 3/SIMD
// (R4-R6's 1536 = 1.5/SIMD was latency-bound at 32% VALU / 13% occ).
// ---------------------------------------------------------------------------
__global__ __launch_bounds__(64)
void k_blur_hw(const float* __restrict__ inE, const float* __restrict__ inG,
               ushort* __restrict__ ws, Taps tp)
{
    const int l    = threadIdx.x;
    const int w0   = (blockIdx.x & 1) * 256;     // W half
    const int r0   = (blockIdx.x >> 1) * 32;     // 16 rowgroups
    const int z    = blockIdx.y;                 // plane 0..95

    const float* src = (z < NPLANES) ? (inE + z * PLANE)
                                     : (inG + (z - NPLANES) * PLANE);

    const int  col   = w0 + 4 * l;               // first of this lane's 4 cols
    const bool is0   = (l == 0);
    const bool is63  = (l == 63);
    const bool ledge = (w0 == 0);                // image edge at left of half
    const bool redge = (w0 + 256 == 512);        // image edge at right of half
    const bool do_halo = (is0 && !ledge) || (is63 && !redge);
    const int  hoff  = is0 ? (w0 - 4) : (w0 + 256);  // halo float4 col
    const int  tile  = col >> 6;                 // w-tile 0..7
    const int  inner = col & 63;

    float ring[10][4];                           // W-blurred rows, slot = j % 10

#define FOLD(r) ((r) < 0 ? (-1 - (r)) : ((r) > 511 ? (1023 - (r)) : (r)))

    // preload rows j=0,1,2 (plane rows r0-4..r0-2)
    float4 pown[3], phal[3];
    phal[0] = phal[1] = phal[2] = make_float4(1.f, 1.f, 1.f, 1.f);
#pragma unroll
    for (int s = 0; s < 3; ++s) {
        const float* rp = src + FOLD(r0 - 4 + s) * 512;
        pown[s] = *(const float4*)(rp + col);
        if (do_halo) phal[s] = *(const float4*)(rp + hoff);
    }

    for (int jb = 0; jb < 40; jb += 10) {
#pragma unroll
        for (int u = 0; u < 10; ++u) {
            const int j = jb + u;                // input row 0..39 (plane r0-4+j)

            float4 own = pown[0], hal = phal[0];
            pown[0] = pown[1]; pown[1] = pown[2];
            phal[0] = phal[1]; phal[1] = phal[2];
            if (j + 3 < 40) {                    // load row j+3 (depth-3 pipe)
                const float* rp = src + FOLD(r0 - 1 + j) * 512;
                pown[2] = *(const float4*)(rp + col);
                if (do_halo) phal[2] = *(const float4*)(rp + hoff);
            }

            const float w4 = __logf(own.x + 1e-6f);
            const float w5 = __logf(own.y + 1e-6f);
            const float w6 = __logf(own.z + 1e-6f);
            const float w7 = __logf(own.w + 1e-6f);
            const float h0 = __logf(hal.x + 1e-6f);  // garbage on non-halo lanes
            const float h1 = __logf(hal.y + 1e-6f);
            const float h2 = __logf(hal.z + 1e-6f);
            const float h3 = __logf(hal.w + 1e-6f);

            float win[12];
            win[4] = w4; win[5] = w5; win[6] = w6; win[7] = w7;
            win[0] = __shfl_up(w4, 1);
            win[1] = __shfl_up(w5, 1);
            win[2] = __shfl_up(w6, 1);
            win[3] = __shfl_up(w7, 1);
            win[8]  = __shfl_down(w4, 1);
            win[9]  = __shfl_down(w5, 1);
            win[10] = __shfl_down(w6, 1);
            win[11] = __shfl_down(w7, 1);
            if (is0) {   // cols col-4..col-1
                if (ledge) { win[0] = w7; win[1] = w6; win[2] = w5; win[3] = w4; }
                else       { win[0] = h0; win[1] = h1; win[2] = h2; win[3] = h3; }
            }
            if (is63) {  // cols col+4..col+7
                if (redge) { win[8] = w7; win[9] = w6; win[10] = w5; win[11] = w4; }
                else       { win[8] = h0; win[9] = h1; win[10] = h2; win[11] = h3; }
            }

            // W-blur -> ring slot u (j%10 == u since jb % 10 == 0)
#pragma unroll
            for (int i = 0; i < 4; ++i) {
                float o = 0.f;
#pragma unroll
                for (int t = 0; t < 9; ++t) o += tp.k[t] * win[i + t];
                ring[u][i] = o;
            }

            // H-blur + fp16 store once 9 rows live (output row r0+j-8)
            if (j >= 8) {
                float acc[4];
#pragma unroll
                for (int i = 0; i < 4; ++i) {
                    float o = 0.f;
#pragma unroll
                    for (int t = 0; t < 9; ++t)
                        o += tp.k[t] * ring[(u + 2 + t) % 10][i];  // row j-8+t
                    acc[i] = o;
                }
                const int ro = r0 + j - 8;
                __half2 pa, pb;
                pa.x = __float2half(acc[0]); pa.y = __float2half(acc[1]);
                pb.x = __float2half(acc[2]); pb.y = __float2half(acc[3]);
                ushort* dp = ws + (((ro * 8 + tile) * 96) + z) * 64 + inner;
                *(uint2*)dp = make_uint2(*(uint*)&pa, *(uint*)&pb);
            }
        }
    }
#undef FOLD
}

// ---------------------------------------------------------------------------
// Kernel 2: C-blur + N-blur + loss, register-light (9-slot ring, 3x3 C-matrix),
// software-pipelined loads; fp16 ws reads; per-block atomicAdd to out.
// grid (1024), block (256); one thread per (h,w).
// ---------------------------------------------------------------------------
__global__ __launch_bounds__(256)
void k_cn_loss(const __half* __restrict__ ws, const float* __restrict__ Ie,
               const float* __restrict__ Ig, float* __restrict__ out,
               Taps tp, CMat cm)
{
    const int tid = threadIdx.x;
    const int hw  = blockIdx.x * 256 + tid;
    const __half* wbase = ws + (hw >> 6) * (96 * 64) + (hw & 63);
    // E plane q at wbase[q*64], G plane q at wbase[(48+q)*64]

    float re[9][3];   // ring of C-blurred smoothed-log(E), slot = m % 9
    float rg[9][3];

#define LOADRAW(m, vE, vG)                                                     \
    vE[0] = __half2float(wbase[((m) * 3 + 0) * 64]);                           \
    vE[1] = __half2float(wbase[((m) * 3 + 1) * 64]);                           \
    vE[2] = __half2float(wbase[((m) * 3 + 2) * 64]);                           \
    vG[0] = __half2float(wbase[(48 + (m) * 3 + 0) * 64]);                      \
    vG[1] = __half2float(wbase[(48 + (m) * 3 + 1) * 64]);                      \
    vG[2] = __half2float(wbase[(48 + (m) * 3 + 2) * 64]);

#define CBLUR(v, dst)                                                          \
    dst[0] = cm.w[0][0] * v[0] + cm.w[0][1] * v[1] + cm.w[0][2] * v[2];        \
    dst[1] = cm.w[1][0] * v[0] + cm.w[1][1] * v[1] + cm.w[1][2] * v[2];        \
    dst[2] = cm.w[2][0] * v[0] + cm.w[2][1] * v[1] + cm.w[2][2] * v[2];

#pragma unroll
    for (int m = 0; m < 4; ++m) {
        float vE[3], vG[3];
        LOADRAW(m, vE, vG);
        CBLUR(vE, re[m]); CBLUR(vG, rg[m]);
    }
    float nvE[3], nvG[3];
    LOADRAW(4, nvE, nvG);
    float ieq[3], igq[3];
#pragma unroll
    for (int c = 0; c < 3; ++c) {
        ieq[c] = Ie[c * PLANE + hw] + 1e-6f;
        igq[c] = Ig[c * PLANE + hw] + 1e-6f;
    }

    float acc = 0.f;
#pragma unroll
    for (int n = 0; n < 16; ++n) {
        float nie[3], nig[3];
        if (n + 1 < 16) {
#pragma unroll
            for (int c = 0; c < 3; ++c) {
                nie[c] = Ie[((n + 1) * 3 + c) * PLANE + hw] + 1e-6f;
                nig[c] = Ig[((n + 1) * 3 + c) * PLANE + hw] + 1e-6f;
            }
        }
        const int mnew = n + 4;
        if (mnew < 16) {
            CBLUR(nvE, re[mnew % 9]); CBLUR(nvG, rg[mnew % 9]);
            if (mnew + 1 < 16) { LOADRAW(mnew + 1, nvE, nvG); }
        }
#pragma unroll
        for (int c = 0; c < 3; ++c) {
            float se = 0.f, sg = 0.f;
#pragma unroll
            for (int t = 0; t < 9; ++t) {
                int m = n - 4 + t;
                m = (m < 0) ? (-1 - m) : ((m > 15) ? (31 - m) : m);  // compile-time
                se += tp.k[t] * re[m % 9][c];
                sg += tp.k[t] * rg[m % 9][c];
            }
            float ee = __expf(-se);                  // 1/Le
            float eg = __expf(-sg);
            float Re = ieq[c] * ee;
            float Rg = igq[c] * eg;
            float Le = __builtin_amdgcn_rcpf(ee);    // exp(se)
            float Lg = __builtin_amdgcn_rcpf(eg);
            float dr = Re - Rg;
            float dl = Le - Lg;
            acc += dr * dr + dl * dl;
        }
        if (n + 1 < 16) {
#pragma unroll
            for (int c = 0; c < 3; ++c) { ieq[c] = nie[c]; igq[c] = nig[c]; }
        }
    }
#undef LOADRAW
#undef CBLUR

    __shared__ float red[256];
    red[tid] = acc;
    __syncthreads();
#pragma unroll
    for (int s = 128; s > 0; s >>= 1) {
        if (tid < s) red[tid] += red[tid + s];
        __syncthreads();
    }
    if (tid == 0) atomicAdd(out, red[0] * (1.0f / (float)NEL));
}

extern "C" void kernel_launch(void* const* d_in, const int* in_sizes, int n_in,
                              void* d_out, int out_size, void* d_ws, size_t ws_size,
                              hipStream_t stream) {
    const float* Ie = (const float*)d_in[0];
    const float* Ig = (const float*)d_in[1];

    // Gaussian taps: sigma=1, radius=int(4*1+0.5)=4, double-precision normalize
    Taps tp;
    {
        double kk[9], s = 0.0;
        for (int i = 0; i < 9; ++i) { double x = (double)(i - 4); kk[i] = exp(-0.5 * x * x); s += kk[i]; }
        for (int i = 0; i < 9; ++i) tp.k[i] = (float)(kk[i] / s);
    }

    // C-axis (size 3) 9-tap symmetric blur collapsed to a 3x3 matrix
    CMat cm;
    {
        for (int c = 0; c < 3; ++c) {
            cm.w[c][0] = cm.w[c][1] = cm.w[c][2] = 0.f;
            for (int t = 0; t < 9; ++t) {
                int m = c - 4 + t;
                int mm = ((m % 6) + 6) % 6;          // symmetric reflect, period 6
                if (mm > 2) mm = 5 - mm;
                cm.w[c][mm] += tp.k[t];
            }
        }
    }

    ushort* ws = (ushort*)d_ws;          // tiled fp16 blurred logs, 48 MB

    hipMemsetAsync(d_out, 0, sizeof(float), stream);  // zero the atomic target
    dim3 g1(32, 96);
    k_blur_hw<<<g1, 64, 0, stream>>>(Ie, Ig, ws, tp);
    k_cn_loss<<<1024, 256, 0, stream>>>((const __half*)ws, Ie, Ig,
                                        (float*)d_out, tp, cm);
}